// Round 12
// baseline (1125.287 us; speedup 1.0000x reference)
//
#include <hip/hip_runtime.h>
#include <cstdint>
#include <cstddef>

// ---------------------------------------------------------------------------
// DualAttention: B=1024, L=196, H=1024, A=512
// R12: weight-panel fragments are read DIRECTLY from L2 into registers (the
// baked-XOR panel layout maps fragment regs <-> panel bytes 1:1, coalesced).
// No LDS B-buffers, no global_load_lds, no manual vmcnt:
//  - k_channel: att-tile staged once (read-only) -> ZERO barriers in K-loop;
//    LDS 33.8KB (was 66.5) -> up to 4 blocks/CU.
//  - k_spatial: only the A-tile double-buffer remains -> ONE barrier/step
//    (LGKM0+SBAR only); LDS 12KB (was 70.6).
// R11's 512-thread blocks retained.
// ---------------------------------------------------------------------------

#define DEVI __device__ __forceinline__

typedef __bf16 bf16;
typedef bf16 bf16x4 __attribute__((ext_vector_type(4)));
typedef bf16 bf16x8 __attribute__((ext_vector_type(8)));
typedef float f32x4 __attribute__((ext_vector_type(4)));
typedef unsigned int uint32;

static constexpr int Bb = 1024;
static constexpr int Ll = 196;
static constexpr int Hh = 1024;
static constexpr int BL = Bb * Ll;        // 200704

#define LGKM0     asm volatile("s_waitcnt lgkmcnt(0)" ::: "memory")
#define SBAR()    __builtin_amdgcn_s_barrier()
#define SCHED0()  __builtin_amdgcn_sched_barrier(0)

DEVI float fast_tanh(float x) {
  float e = __expf(2.f * x);
  return 1.f - 2.f * __builtin_amdgcn_rcpf(e + 1.f);
}

DEVI uint32 packbf2(float a, float b) {
  union { bf16 h; unsigned short u; } x, y;
  x.h = (bf16)a; y.h = (bf16)b;
  return (uint32)x.u | ((uint32)y.u << 16);
}

// --------------------- weight panel builders (run once) --------------------
// Panels: [k0/32][a=0..511][64B]; 16B slot s holds k-octet (s ^ g(a)),
// g(a) = (a>>1)&3.  Fragment read: row a, slot l4^g(a) -> k-octet l4.
__global__ void k_build_wt(const float* __restrict__ W, bf16* __restrict__ P) {
  int idx = blockIdx.x * 256 + threadIdx.x;      // 65536
  int a = idx & 511;
  int ko = (idx >> 9) << 3;
  bf16x8 v;
#pragma unroll
  for (int j = 0; j < 8; ++j) v[j] = (bf16)W[(size_t)(ko + j) * 512 + a];
  int panel = ko >> 5;
  int slot = ((ko >> 3) & 3) ^ ((a >> 1) & 3);
  *reinterpret_cast<bf16x8*>((char*)P + (size_t)panel * 32768 + a * 64 + slot * 16) = v;
}

__global__ void k_build_wct(const float* __restrict__ W, bf16* __restrict__ P) {
  int idx = blockIdx.x * 256 + threadIdx.x;      // 14336
  int a = idx & 511;
  int lo = (idx >> 9) << 3;
  bf16x8 v;
#pragma unroll
  for (int j = 0; j < 8; ++j)
    v[j] = (lo + j < Ll) ? (bf16)W[(size_t)(lo + j) * 512 + a] : (bf16)0.f;
  int panel = lo >> 5;
  int slot = ((lo >> 3) & 3) ^ ((a >> 1) & 3);
  *reinterpret_cast<bf16x8*>((char*)P + (size_t)panel * 32768 + a * 64 + slot * 16) = v;
}

// ------------------------------- p_h = h@W_h -------------------------------
__global__ void k_ph(const float* __restrict__ h, const float* __restrict__ W_h,
                     const float* __restrict__ b_h, float* __restrict__ p_h) {
  int a = blockIdx.x * 256 + threadIdx.x;
  int b0 = blockIdx.y * 8;
  float acc[8] = {0.f, 0.f, 0.f, 0.f, 0.f, 0.f, 0.f, 0.f};
  for (int k = 0; k < 1024; ++k) {
    float w = W_h[(size_t)k * 512 + a];
#pragma unroll
    for (int i = 0; i < 8; ++i) acc[i] += h[(size_t)(b0 + i) * 1024 + k] * w;
  }
#pragma unroll
  for (int i = 0; i < 8; ++i) p_h[(size_t)(b0 + i) * 512 + a] = acc[i] + b_h[a];
}

// ---------------- spatial branch: fused GEMM + tanh-dot reduce -------------
// grid = BL/64 = 3136, 512 thr (8 waves; wave wn owns cols wn*64..+63).
// LDS 12288: A dbuf 2x5120 only.  B fragments straight from L2 (WtP).
// One barrier per k-step (LGKM0+SBAR).
#define SPA(p) ((p) * 5120)
#define SP_ASTR 80
__launch_bounds__(512)
__global__ void k_spatial(const float* __restrict__ att, const bf16* __restrict__ WtP,
                          const float* __restrict__ b_att, const float* __restrict__ p_h,
                          const float* __restrict__ w_alpha, float* __restrict__ logits_s) {
  __shared__ alignas(1024) char lds[12288];
  const int tid = threadIdx.x;
  const int lane = tid & 63;
  const int wn = tid >> 6;                  // 0..7
  const int l15 = lane & 15, l4 = lane >> 4;
  const size_t row0 = (size_t)blockIdx.x * 64;
  const int slotP = (l4 ^ ((l15 >> 1) & 3)) << 4;
  const int ar = tid >> 3;                  // A rows 0..63
  const int aks = (tid & 7) << 2;           // k offset 0,4,...,28
  const char* WtPc = (const char*)WtP;
  const float* apbase = att + (row0 + ar) * 1024 + aks;
  // per-wave B fragment base offsets (within a panel)
  int boff[4];
#pragma unroll
  for (int n = 0; n < 4; ++n) boff[n] = (wn * 64 + n * 16 + l15) * 64 + slotP;

  f32x4 acc[4][4];
#pragma unroll
  for (int m = 0; m < 4; ++m)
#pragma unroll
    for (int n = 0; n < 4; ++n) acc[m][n] = f32x4{0.f, 0.f, 0.f, 0.f};

  // prologue: A(0)->Abuf0; prefetch A(1),A(2) into regs
  float4 c0x = *reinterpret_cast<const float4*>(apbase);
  float4 c1x = *reinterpret_cast<const float4*>(apbase + 32);
  {
    bf16x4 w0 = {(bf16)c0x.x, (bf16)c0x.y, (bf16)c0x.z, (bf16)c0x.w};
    *reinterpret_cast<bf16x4*>(&lds[SPA(0) + ar * SP_ASTR + (aks << 1)]) = w0;
  }
  c0x = *reinterpret_cast<const float4*>(apbase + 64);
  LGKM0;
  SCHED0();
  SBAR();                                  // Abuf0 ready
  SCHED0();

  for (int t = 0; t < 32; ++t) {
    const int p = t & 1;
    // B(t) fragments from L2 (coalesced 1KB runs per wave)
    const char* bpan = WtPc + (size_t)t * 32768;
    bf16x8 bv[4];
#pragma unroll
    for (int n = 0; n < 4; ++n)
      bv[n] = *reinterpret_cast<const bf16x8*>(bpan + boff[n]);
    // A fragments from LDS
    bf16x8 af[4];
#pragma unroll
    for (int m = 0; m < 4; ++m)
      af[m] = *reinterpret_cast<const bf16x8*>(
          &lds[SPA(p) + (m * 16 + l15) * SP_ASTR + (l4 << 4)]);
    // stage A(t+1) into the other buffer; refill the freed reg with A(t+3)
    if (t < 31) {
      const int awoff = SPA(p ^ 1) + ar * SP_ASTR + (aks << 1);
      if ((t & 1) == 0) {
        bf16x4 w0 = {(bf16)c1x.x, (bf16)c1x.y, (bf16)c1x.z, (bf16)c1x.w};
        *reinterpret_cast<bf16x4*>(&lds[awoff]) = w0;
        if (t <= 28)
          c1x = *reinterpret_cast<const float4*>(apbase + (t + 3) * 32);
      } else {
        bf16x4 w0 = {(bf16)c0x.x, (bf16)c0x.y, (bf16)c0x.z, (bf16)c0x.w};
        *reinterpret_cast<bf16x4*>(&lds[awoff]) = w0;
        if (t <= 28)
          c0x = *reinterpret_cast<const float4*>(apbase + (t + 3) * 32);
      }
    }
#pragma unroll
    for (int n = 0; n < 4; ++n)
#pragma unroll
      for (int m = 0; m < 4; ++m)
        acc[m][n] = __builtin_amdgcn_mfma_f32_16x16x32_bf16(af[m], bv[n], acc[m][n], 0, 0, 0);
    LGKM0;                                 // af reads + A(t+1) write drained
    SCHED0();
    SBAR();                                // single barrier per step
    SCHED0();
  }

  // epilogue: wave wn covers cols wn*64..+63 of all 64 rows
  float wa[4], ba[4], ph0[4], ph1[4];
  unsigned b0i = (unsigned)row0 / 196u;
  unsigned b1i = (unsigned)(row0 + 63) / 196u;
  unsigned bnd = (b0i + 1) * 196u;
#pragma unroll
  for (int n = 0; n < 4; ++n) {
    int a = wn * 64 + n * 16 + l15;
    wa[n] = w_alpha[a];
    ba[n] = b_att[a];
    ph0[n] = p_h[(size_t)b0i * 512 + a];
    ph1[n] = p_h[(size_t)b1i * 512 + a];
  }
  float* red = reinterpret_cast<float*>(lds);   // 8x64 floats (Abuf area free)
#pragma unroll
  for (int m = 0; m < 4; ++m) {
#pragma unroll
    for (int j = 0; j < 4; ++j) {
      int rloc = m * 16 + l4 * 4 + j;
      unsigned R = (unsigned)row0 + rloc;
      bool hib = R >= bnd;
      float s = 0.f;
#pragma unroll
      for (int n = 0; n < 4; ++n)
        s += fast_tanh(acc[m][n][j] + ba[n] + (hib ? ph1[n] : ph0[n])) * wa[n];
      s += __shfl_xor(s, 1);
      s += __shfl_xor(s, 2);
      s += __shfl_xor(s, 4);
      s += __shfl_xor(s, 8);
      if (l15 == 0) red[wn * 64 + rloc] = s;
    }
  }
  __syncthreads();
  if (tid < 64) {
    float r = 0.f;
#pragma unroll
    for (int w = 0; w < 8; ++w) r += red[w * 64 + tid];
    logits_s[row0 + tid] = r;
  }
}

// ---------------- channel branch: fused GEMM + tanh-dot reduce -------------
// grid = (16 h-tiles, 1024 b), 512 thr. D[a,h] = sum_l Wct[a,l]*att[b,l,h].
// att-tile staged ONCE (64h x 224l bf16, stride 464, quad swizzle) by waves
// 0-3; panel fragments straight from L2 (WctP). ZERO barriers in the K-loop.
// Half-panel s (s=0..13): rows (s/7)*256 + [0,256) of panel (s%7).
#define CT_STR 464
#define CH_PHC 29696
#define CH_WB  31744
__launch_bounds__(512)
__global__ void k_channel(const float* __restrict__ att, const bf16* __restrict__ WctP,
                          const float* __restrict__ b_ch, const float* __restrict__ p_h,
                          const float* __restrict__ w_beta, float* __restrict__ logits_c) {
  __shared__ alignas(1024) char lds[33792];
  const int tid = threadIdx.x;
  const int lane = tid & 63;
  const int wn = tid >> 6;                  // 0..7
  const int l15 = lane & 15, l4 = lane >> 4;
  const int b = blockIdx.y;
  const int h0 = blockIdx.x * 64;
  const float* attb = att + (size_t)b * Ll * 1024 + h0;
  const char* Pc = (const char*)WctP;
  const int slotP = (l4 ^ ((l15 >> 1) & 3)) << 4;     // panel frag slot
  const int slotT = (l4 ^ ((l15 >> 2) & 3)) << 4;     // tile frag slot
  const int lp = (tid >> 4) & 15;                     // l-pair 0..15 (tid<256)
  const int hq = (tid & 15) << 2;                     // h 0,4,...,60
  const int usw = lp ^ ((tid & 3) << 2);              // write-side swizzled col
  // per-wave panel fragment offsets (row within a 256-row half)
  int poff[2];
#pragma unroll
  for (int m = 0; m < 2; ++m) poff[m] = (wn * 32 + m * 16 + l15) * 64 + slotP;

  // ---- params (1 each per thread) ----
  float pr = p_h[(size_t)b * 512 + tid];
  float bc = b_ch[tid];
  float wb = w_beta[tid];
  // ---- whole att tile -> regs, waves 0-3 only (coalesced 256B runs) ----
  float4 va[7], vb[7];
  if (tid < 256) {
#pragma unroll
    for (int ch = 0; ch < 7; ++ch) {
      int lg = ch * 32 + 2 * lp;
      va[ch] = float4{0.f, 0.f, 0.f, 0.f};
      vb[ch] = float4{0.f, 0.f, 0.f, 0.f};
      if (lg < Ll)
        va[ch] = *reinterpret_cast<const float4*>(&attb[(size_t)lg * 1024 + hq]);
      if (lg + 1 < Ll)
        vb[ch] = *reinterpret_cast<const float4*>(&attb[(size_t)(lg + 1) * 1024 + hq]);
    }
#pragma unroll
    for (int ch = 0; ch < 7; ++ch) {
      uint32 pk[4] = {packbf2(va[ch].x, vb[ch].x), packbf2(va[ch].y, vb[ch].y),
                      packbf2(va[ch].z, vb[ch].z), packbf2(va[ch].w, vb[ch].w)};
#pragma unroll
      for (int c = 0; c < 4; ++c)
        *reinterpret_cast<uint32*>(
            &lds[(hq + c) * CT_STR + ch * 64 + 4 * usw]) = pk[c];
    }
  }
  // ---- params to LDS ----
  {
    float* phcL = reinterpret_cast<float*>(&lds[CH_PHC]);
    float* wbL = reinterpret_cast<float*>(&lds[CH_WB]);
    phcL[tid] = pr + bc;
    wbL[tid] = wb;
  }

  f32x4 acc[2][4];
#pragma unroll
  for (int m = 0; m < 2; ++m)
#pragma unroll
    for (int n = 0; n < 4; ++n) acc[m][n] = f32x4{0.f, 0.f, 0.f, 0.f};
  float sn[4] = {0.f, 0.f, 0.f, 0.f};
  const float* phcLc = reinterpret_cast<const float*>(&lds[CH_PHC]);
  const float* wbLc = reinterpret_cast<const float*>(&lds[CH_WB]);

  LGKM0;
  SCHED0();
  SBAR();                                  // tile + params ready (only barrier)
  SCHED0();

  // ---- K-loop, half 0 (a in [0,256)): NO barriers ----
#pragma unroll 2
  for (int s = 0; s < 7; ++s) {
    const char* pan = Pc + (size_t)s * 32768;
    bf16x8 av[2], bv[4];
#pragma unroll
    for (int m = 0; m < 2; ++m)
      av[m] = *reinterpret_cast<const bf16x8*>(pan + poff[m]);
#pragma unroll
    for (int n = 0; n < 4; ++n)
      bv[n] = *reinterpret_cast<const bf16x8*>(
          &lds[(n * 16 + l15) * CT_STR + s * 64 + slotT]);
#pragma unroll
    for (int n = 0; n < 4; ++n)
#pragma unroll
      for (int m = 0; m < 2; ++m)
        acc[m][n] = __builtin_amdgcn_mfma_f32_16x16x32_bf16(av[m], bv[n], acc[m][n], 0, 0, 0);
  }
  // epilogue half 0, reset acc
#pragma unroll
  for (int m = 0; m < 2; ++m) {
    int abase = wn * 32 + m * 16 + l4 * 4;
    float4 p4 = *reinterpret_cast<const float4*>(&phcLc[abase]);
    float4 w4 = *reinterpret_cast<const float4*>(&wbLc[abase]);
#pragma unroll
    for (int n = 0; n < 4; ++n) {
      sn[n] += fast_tanh(acc[m][n][0] + p4.x) * w4.x;
      sn[n] += fast_tanh(acc[m][n][1] + p4.y) * w4.y;
      sn[n] += fast_tanh(acc[m][n][2] + p4.z) * w4.z;
      sn[n] += fast_tanh(acc[m][n][3] + p4.w) * w4.w;
      acc[m][n] = f32x4{0.f, 0.f, 0.f, 0.f};
    }
  }
  // ---- K-loop, half 1 (a in [256,512)) ----
#pragma unroll 2
  for (int s = 0; s < 7; ++s) {
    const char* pan = Pc + (size_t)s * 32768 + 16384;
    bf16x8 av[2], bv[4];
#pragma unroll
    for (int m = 0; m < 2; ++m)
      av[m] = *reinterpret_cast<const bf16x8*>(pan + poff[m]);
#pragma unroll
    for (int n = 0; n < 4; ++n)
      bv[n] = *reinterpret_cast<const bf16x8*>(
          &lds[(n * 16 + l15) * CT_STR + s * 64 + slotT]);
#pragma unroll
    for (int n = 0; n < 4; ++n)
#pragma unroll
      for (int m = 0; m < 2; ++m)
        acc[m][n] = __builtin_amdgcn_mfma_f32_16x16x32_bf16(av[m], bv[n], acc[m][n], 0, 0, 0);
  }
  // epilogue half 1
#pragma unroll
  for (int m = 0; m < 2; ++m) {
    int abase = 256 + wn * 32 + m * 16 + l4 * 4;
    float4 p4 = *reinterpret_cast<const float4*>(&phcLc[abase]);
    float4 w4 = *reinterpret_cast<const float4*>(&wbLc[abase]);
#pragma unroll
    for (int n = 0; n < 4; ++n) {
      sn[n] += fast_tanh(acc[m][n][0] + p4.x) * w4.x;
      sn[n] += fast_tanh(acc[m][n][1] + p4.y) * w4.y;
      sn[n] += fast_tanh(acc[m][n][2] + p4.z) * w4.z;
      sn[n] += fast_tanh(acc[m][n][3] + p4.w) * w4.w;
    }
  }
#pragma unroll
  for (int n = 0; n < 4; ++n) {
    sn[n] += __shfl_xor(sn[n], 16);
    sn[n] += __shfl_xor(sn[n], 32);
  }
  __syncthreads();                          // tile reads done; reuse LDS
  float* red = reinterpret_cast<float*>(lds);   // 8x64 floats
  if (l4 == 0) {
#pragma unroll
    for (int n = 0; n < 4; ++n) red[wn * 64 + n * 16 + l15] = sn[n];
  }
  __syncthreads();
  if (tid < 64) {
    float r = 0.f;
#pragma unroll
    for (int w = 0; w < 8; ++w) r += red[w * 64 + tid];
    logits_c[(size_t)b * 1024 + h0 + tid] = r;
  }
}

// ------------------------------- softmaxes ---------------------------------
__global__ void k_softmax_s(const float* __restrict__ logits, float* __restrict__ wout) {
  int b = blockIdx.x, t = threadIdx.x;
  __shared__ float sm[8];
  float x = (t < Ll) ? logits[(size_t)b * Ll + t] : -1e30f;
  float m = x;
#pragma unroll
  for (int o = 32; o; o >>= 1) m = fmaxf(m, __shfl_xor(m, o));
  if ((t & 63) == 0) sm[t >> 6] = m;
  __syncthreads();
  m = fmaxf(fmaxf(sm[0], sm[1]), fmaxf(sm[2], sm[3]));
  float e = (t < Ll) ? __expf(x - m) : 0.f;
  float s = e;
#pragma unroll
  for (int o = 32; o; o >>= 1) s += __shfl_xor(s, o);
  if ((t & 63) == 0) sm[4 + (t >> 6)] = s;
  __syncthreads();
  s = sm[4] + sm[5] + sm[6] + sm[7];
  if (t < Ll) wout[(size_t)b * Ll + t] = e / s;
}

__global__ void k_softmax_c(const float* __restrict__ logits, float* __restrict__ wout) {
  int b = blockIdx.x, t = threadIdx.x;
  __shared__ float sm[8];
  float4 x = *reinterpret_cast<const float4*>(&logits[(size_t)b * 1024 + (t << 2)]);
  float m = fmaxf(fmaxf(x.x, x.y), fmaxf(x.z, x.w));
#pragma unroll
  for (int o = 32; o; o >>= 1) m = fmaxf(m, __shfl_xor(m, o));
  if ((t & 63) == 0) sm[t >> 6] = m;
  __syncthreads();
  m = fmaxf(fmaxf(sm[0], sm[1]), fmaxf(sm[2], sm[3]));
  float e0 = __expf(x.x - m), e1 = __expf(x.y - m);
  float e2 = __expf(x.z - m), e3 = __expf(x.w - m);
  float s = e0 + e1 + e2 + e3;
#pragma unroll
  for (int o = 32; o; o >>= 1) s += __shfl_xor(s, o);
  if ((t & 63) == 0) sm[4 + (t >> 6)] = s;
  __syncthreads();
  float r = 1.f / (sm[4] + sm[5] + sm[6] + sm[7]);
  float4 o4 = {e0 * r, e1 * r, e2 * r, e3 * r};
  *reinterpret_cast<float4*>(&wout[(size_t)b * 1024 + (t << 2)]) = o4;
}

// --------------- fused weighted sums: one pass over att --------------------
__launch_bounds__(256)
__global__ void k_weighted(const float* __restrict__ att, const float* __restrict__ wsp,
                           const float* __restrict__ wch, float* __restrict__ out_s,
                           float* __restrict__ out_c) {
  int b = blockIdx.x, t = threadIdx.x;
  int lane = t & 63, wave = t >> 6;
  __shared__ float wsl[Ll];
  __shared__ float chan[4][Ll];
  if (t < Ll) wsl[t] = wsp[(size_t)b * Ll + t];
  float4 wc = *reinterpret_cast<const float4*>(&wch[(size_t)b * 1024 + (t << 2)]);
  float4 accs = {0.f, 0.f, 0.f, 0.f};
  __syncthreads();
  const float* attb = att + (size_t)b * Ll * 1024;
  for (int l = 0; l < Ll; ++l) {
    float4 v = *reinterpret_cast<const float4*>(&attb[(size_t)l * 1024 + (t << 2)]);
    float w = wsl[l];
    accs.x += w * v.x; accs.y += w * v.y; accs.z += w * v.z; accs.w += w * v.w;
    float pc = wc.x * v.x + wc.y * v.y + wc.z * v.z + wc.w * v.w;
#pragma unroll
    for (int o = 32; o; o >>= 1) pc += __shfl_xor(pc, o);
    if (lane == 0) chan[wave][l] = pc;
  }
  *reinterpret_cast<float4*>(&out_s[(size_t)b * 1024 + (t << 2)]) = accs;
  __syncthreads();
  if (t < Ll)
    out_c[(size_t)b * Ll + t] = chan[0][t] + chan[1][t] + chan[2][t] + chan[3][t];
}

// ------------------------------- launcher ----------------------------------
extern "C" void kernel_launch(void* const* d_in, const int* in_sizes, int n_in,
                              void* d_out, int out_size, void* d_ws, size_t ws_size,
                              hipStream_t stream) {
  (void)in_sizes; (void)n_in; (void)out_size; (void)ws_size;
  const float* att     = (const float*)d_in[0];
  const float* h       = (const float*)d_in[1];
  const float* W_att   = (const float*)d_in[2];
  const float* b_att   = (const float*)d_in[3];
  const float* W_h     = (const float*)d_in[4];
  const float* b_h     = (const float*)d_in[5];
  const float* w_alpha = (const float*)d_in[6];
  const float* W_ch    = (const float*)d_in[8];
  const float* b_ch    = (const float*)d_in[9];
  const float* w_beta  = (const float*)d_in[10];
  // d_in[7] b_alpha, d_in[11] b_beta: softmax-shift-invariant, unused

  float* out_ws    = (float*)d_out;                       // [B,H]
  float* out_wc    = out_ws + (size_t)Bb * Hh;            // [B,L]
  float* out_wspat = out_wc + (size_t)Bb * Ll;            // [B,L]

  char* ws = (char*)d_ws;
  float* p_h      = (float*)(ws);                          // 2 MB
  float* logits_s = (float*)(ws + 2097152);                // 802816 B
  float* logits_c = (float*)(ws + 2899968);                // 4 MB
  float* w_chan   = (float*)(ws + 7094272);                // 4 MB
  bf16*  WtP      = (bf16*)(ws + 11288576);                // 1 MB (32 panels)
  bf16*  WctP     = (bf16*)(ws + 12337152);                // 224 KB (7 panels)

  k_build_wt<<<256, 256, 0, stream>>>(W_att, WtP);
  k_build_wct<<<56, 256, 0, stream>>>(W_ch, WctP);
  k_ph<<<dim3(2, 128), 256, 0, stream>>>(h, W_h, b_h, p_h);
  k_spatial<<<BL / 64, 512, 0, stream>>>(att, WtP, b_att, p_h, w_alpha, logits_s);
  k_channel<<<dim3(16, 1024), 512, 0, stream>>>(att, WctP, b_ch, p_h, w_beta, logits_c);
  k_softmax_s<<<1024, 256, 0, stream>>>(logits_s, out_wspat);
  k_softmax_c<<<1024, 256, 0, stream>>>(logits_c, w_chan);
  k_weighted<<<1024, 256, 0, stream>>>(att, out_wspat, w_chan, out_ws, out_wc);
}